// Round 3
// baseline (567.287 us; speedup 1.0000x reference)
//
#include <hip/hip_runtime.h>
#include <hip/hip_bf16.h>
#include <math.h>

// ---------------------------------------------------------------------------
// DotScaledAttention: q=(x0@Wq+bq)/sqrt(512); k=x1@Wk+bk; v=x2@Wk+bk;
// out = causal_softmax(q k^T) v.   B=8 N=2048 d_emb=1024 d_red=512, fp32 io.
// R4: proj 128x128 tiles + XCD-group swizzle (FETCH 808->130MB).
// R5: proj K-loop software pipeline (prefetch to regs under MFMA phase).
// R6: attn DMA pipeline deepened to 2 chunks in flight (quad buffer,
// vmcnt(8) steady-state wait; chunk a lives in buf a&3 so DMA writes are
// >=2 barriers after the last reads of that buf). s_setprio around MFMA.
// ---------------------------------------------------------------------------

typedef __bf16 bf16_t;
typedef __attribute__((ext_vector_type(8))) __bf16 bf16x8;
typedef __attribute__((ext_vector_type(4))) __bf16 bf16x4;
typedef __attribute__((ext_vector_type(4))) float f32x4;

#define MFMA16(a, b, c) __builtin_amdgcn_mfma_f32_16x16x32_bf16((a), (b), (c), 0, 0, 0)

#define XSTR 72  // LDS row stride (bf16 elems), 144B = 16B-aligned

__device__ __forceinline__ void stage16(const void* g, void* l) {
  // async global->LDS DMA, 16B per lane; LDS dest = wave-uniform base + lane*16
  __builtin_amdgcn_global_load_lds(
      (__attribute__((address_space(1))) void*)(uintptr_t)g,
      (__attribute__((address_space(3))) void*)l, 16, 0, 0);
}

// pipeline waits: raw s_barrier, NO full vmcnt drain in steady state.
// 0x0F78 = vmcnt(8) (2 chunks x 4 loads/wave stay in flight),
// 0x0F74 = vmcnt(4), 0x0F70 = vmcnt(0).
#define PIPE_VM8                                \
  {                                             \
    asm volatile("" ::: "memory");              \
    __builtin_amdgcn_s_waitcnt(0x0F78);         \
    __builtin_amdgcn_s_barrier();               \
    asm volatile("" ::: "memory");              \
  }
#define PIPE_VM4                                \
  {                                             \
    asm volatile("" ::: "memory");              \
    __builtin_amdgcn_s_waitcnt(0x0F74);         \
    __builtin_amdgcn_s_barrier();               \
    asm volatile("" ::: "memory");              \
  }
#define PIPE_VM0                                \
  {                                             \
    asm volatile("" ::: "memory");              \
    __builtin_amdgcn_s_waitcnt(0x0F70);         \
    __builtin_amdgcn_s_barrier();               \
    asm volatile("" ::: "memory");              \
  }

// proj barriers: A = ds_write visibility (lgkm drain only, no vmcnt drain);
// B = write-after-read protection, sched_barrier(0) pins MFMA above and the
// prefetch-consuming cvt/ds_write below, so the vmcnt wait lands post-MFMA.
#define PROJ_BAR_A                                    \
  {                                                   \
    asm volatile("s_waitcnt lgkmcnt(0)" ::: "memory"); \
    __builtin_amdgcn_s_barrier();                     \
    asm volatile("" ::: "memory");                    \
  }
#define PROJ_BAR_B                                    \
  {                                                   \
    __builtin_amdgcn_sched_barrier(0);                \
    __builtin_amdgcn_s_barrier();                     \
    asm volatile("" ::: "memory");                    \
  }

// --------------------------- W transpose + convert --------------------------
__global__ __launch_bounds__(256) void wt_kernel(const float* __restrict__ Wq,
                                                 const float* __restrict__ Wk,
                                                 bf16_t* __restrict__ Wtq,
                                                 bf16_t* __restrict__ Wtk) {
  __shared__ float tile[32][33];
  int bid = blockIdx.x;
  int mat = bid >> 9;
  int rem = bid & 511;
  int kt = rem >> 4, nt = rem & 15;
  int k0 = kt * 32, n0 = nt * 32;
  const float* src = mat ? Wk : Wq;
  bf16_t* dst = mat ? Wtk : Wtq;
  int t = threadIdx.x;
  int r = t >> 3, c4 = (t & 7) * 4;
  float4 v = *(const float4*)(src + (k0 + r) * 512 + n0 + c4);
  tile[r][c4 + 0] = v.x; tile[r][c4 + 1] = v.y;
  tile[r][c4 + 2] = v.z; tile[r][c4 + 3] = v.w;
  __syncthreads();
  bf16x4 o;
  o[0] = (bf16_t)tile[c4 + 0][r];
  o[1] = (bf16_t)tile[c4 + 1][r];
  o[2] = (bf16_t)tile[c4 + 2][r];
  o[3] = (bf16_t)tile[c4 + 3][r];
  *(bf16x4*)(dst + (n0 + r) * 1024 + k0 + c4) = o;
}

// ------------------------------- projections --------------------------------
// 128x128 output tile per block. Grid = 1536 = 3 mats x 128 mblk x 4 nblk.
// Swizzle: xcd = bid&7; i = bid>>3; nblk = i&3; g = (i>>2)*8 + xcd;
// mat = g>>7; mblk = g&127.  The 4 nblk jobs of a (mat,mblk) group are
// consecutive on one XCD -> the 512KB x-slab is fetched from HBM once and
// served 3x from that XCD's L2.
__global__ __launch_bounds__(256, 3) void proj_kernel(
    const float* __restrict__ x0, const float* __restrict__ x1, const float* __restrict__ x2,
    const bf16_t* __restrict__ Wtq, const bf16_t* __restrict__ Wtk,
    const float* __restrict__ bq, const float* __restrict__ bk,
    bf16_t* __restrict__ qo, bf16_t* __restrict__ ko, bf16_t* __restrict__ vT) {
  __shared__ __align__(16) bf16_t Xs[128 * XSTR];
  __shared__ __align__(16) bf16_t Ws[128 * XSTR];
  int bid = blockIdx.x;
  int xcd = bid & 7;
  int i5 = bid >> 3;           // 0..191
  int nblk = i5 & 3;           // 0..3  (128-wide output column tile)
  int g = (i5 >> 2) * 8 + xcd; // 0..383 bijective
  int mat = g >> 7;            // 0..2
  int mblk = g & 127;          // 0..127
  const float* xsrc = (mat == 0) ? x0 : ((mat == 1) ? x1 : x2);
  const bf16_t* wsrc = (mat == 0) ? Wtq : Wtk;
  int tid = threadIdx.x;
  int wave = tid >> 6, lane = tid & 63, lhi = lane >> 4, llo = lane & 15;

  f32x4 acc[2][8];
#pragma unroll
  for (int i = 0; i < 2; ++i)
#pragma unroll
    for (int j = 0; j < 8; ++j) acc[i][j] = (f32x4){0.f, 0.f, 0.f, 0.f};

  int xrow = tid >> 1, xseg = tid & 1;   // 128 rows x 2 segs of 32 K-elems
  int wrow = tid >> 1, wseg = tid & 1;
  const float* xbase = xsrc + (size_t)(mblk * 128 + xrow) * 1024 + xseg * 32;
  const bf16_t* wbase = wsrc + (size_t)(nblk * 128 + wrow) * 1024 + wseg * 32;

  // prefetch registers (kt+1's data lives here during kt's MFMA phase)
  float4 nx[8];
  bf16x8 nw[4];

  // prologue: load kt=0 and stage to LDS
#pragma unroll
  for (int i = 0; i < 8; ++i) nx[i] = *(const float4*)(xbase + i * 4);
#pragma unroll
  for (int i = 0; i < 4; ++i) nw[i] = *(const bf16x8*)(wbase + i * 8);
  {
    bf16_t tmp[32];
#pragma unroll
    for (int i = 0; i < 8; ++i) {
      tmp[i * 4 + 0] = (bf16_t)nx[i].x; tmp[i * 4 + 1] = (bf16_t)nx[i].y;
      tmp[i * 4 + 2] = (bf16_t)nx[i].z; tmp[i * 4 + 3] = (bf16_t)nx[i].w;
    }
#pragma unroll
    for (int i = 0; i < 4; ++i)
      *(bf16x8*)(&Xs[xrow * XSTR + xseg * 32 + i * 8]) = *(bf16x8*)(&tmp[i * 8]);
#pragma unroll
    for (int i = 0; i < 4; ++i)
      *(bf16x8*)(&Ws[wrow * XSTR + wseg * 32 + i * 8]) = nw[i];
  }

  for (int kt = 0; kt < 16; ++kt) {
    PROJ_BAR_A;  // ds_writes visible; prefetch loads NOT drained
    if (kt < 15) {
      int k0 = (kt + 1) * 64;
#pragma unroll
      for (int i = 0; i < 8; ++i) nx[i] = *(const float4*)(xbase + k0 + i * 4);
#pragma unroll
      for (int i = 0; i < 4; ++i) nw[i] = *(const bf16x8*)(wbase + k0 + i * 8);
    }
    // MFMA phase on the current LDS tile (loads in flight underneath)
#pragma unroll
    for (int ks = 0; ks < 2; ++ks) {
      bf16x8 af[2], bfr[8];
#pragma unroll
      for (int mt = 0; mt < 2; ++mt)
        af[mt] = *(const bf16x8*)(&Xs[(wave * 32 + mt * 16 + llo) * XSTR + ks * 32 + lhi * 8]);
#pragma unroll
      for (int nt = 0; nt < 8; ++nt)
        bfr[nt] = *(const bf16x8*)(&Ws[(nt * 16 + llo) * XSTR + ks * 32 + lhi * 8]);
#pragma unroll
      for (int mt = 0; mt < 2; ++mt)
#pragma unroll
        for (int nt = 0; nt < 8; ++nt)
          acc[mt][nt] = MFMA16(af[mt], bfr[nt], acc[mt][nt]);
    }
    if (kt < 15) {
      PROJ_BAR_B;  // reads done; vmcnt wait for nx/nw lands HERE, post-MFMA
      bf16_t tmp[32];
#pragma unroll
      for (int i = 0; i < 8; ++i) {
        tmp[i * 4 + 0] = (bf16_t)nx[i].x; tmp[i * 4 + 1] = (bf16_t)nx[i].y;
        tmp[i * 4 + 2] = (bf16_t)nx[i].z; tmp[i * 4 + 3] = (bf16_t)nx[i].w;
      }
#pragma unroll
      for (int i = 0; i < 4; ++i)
        *(bf16x8*)(&Xs[xrow * XSTR + xseg * 32 + i * 8]) = *(bf16x8*)(&tmp[i * 8]);
#pragma unroll
      for (int i = 0; i < 4; ++i)
        *(bf16x8*)(&Ws[wrow * XSTR + wseg * 32 + i * 8]) = nw[i];
    }
  }

  const float* bias = (mat == 0) ? bq : bk;
  float scale = (mat == 0) ? 0.044194173824159216f : 1.0f;  // 1/sqrt(512)
#pragma unroll
  for (int mt = 0; mt < 2; ++mt) {
#pragma unroll
    for (int nt = 0; nt < 8; ++nt) {
      int n = nblk * 128 + nt * 16 + llo;
      float bv = bias[n];
      int rowb = mblk * 128 + wave * 32 + mt * 16 + lhi * 4;
      float vals[4];
#pragma unroll
      for (int r = 0; r < 4; ++r) vals[r] = (acc[mt][nt][r] + bv) * scale;
      if (mat == 0) {
#pragma unroll
        for (int r = 0; r < 4; ++r) qo[(size_t)(rowb + r) * 512 + n] = (bf16_t)vals[r];
      } else if (mat == 1) {
#pragma unroll
        for (int r = 0; r < 4; ++r) ko[(size_t)(rowb + r) * 512 + n] = (bf16_t)vals[r];
      } else {
        int batch = rowb >> 11, tok = rowb & 2047;
        bf16x4 o;
        o[0] = (bf16_t)vals[0]; o[1] = (bf16_t)vals[1];
        o[2] = (bf16_t)vals[2]; o[3] = (bf16_t)vals[3];
        *(bf16x4*)(vT + (size_t)(batch * 512 + n) * 2048 + tok) = o;
      }
    }
  }
}

// ------------------------- attention: staging helpers ------------------------
// K chunk: 64 keys x 128 d (d-range cd*128..) -> 16KB buf.
// granule idx: key = idx>>4, physical seg p = idx&15, logical seg s = p^(key&7)
__device__ __forceinline__ void issueK(const bf16_t* kbase, int key0, int cd,
                                       bf16_t* buf, int wave, int lane) {
#pragma unroll
  for (int i = 0; i < 4; ++i) {
    int idx = wave * 256 + i * 64 + lane;
    int key = idx >> 4, p = idx & 15;
    int s = p ^ (key & 7);
    stage16(kbase + (size_t)(key0 + key) * 512 + cd * 128 + s * 8,
            buf + (size_t)(wave * 256 + i * 64) * 8);
  }
}
// V chunk: 128 d (cv*128..) x 64 keys -> 16KB buf.
// granule idx: dl = idx>>3, p = idx&7, s = p^(dl&7)
__device__ __forceinline__ void issueV(const bf16_t* vbase, int key0, int cv,
                                       bf16_t* buf, int wave, int lane) {
#pragma unroll
  for (int i = 0; i < 4; ++i) {
    int idx = wave * 256 + i * 64 + lane;
    int dl = idx >> 3, p = idx & 7;
    int s = p ^ (dl & 7);
    stage16(vbase + (size_t)(cv * 128 + dl) * 2048 + key0 + s * 8,
            buf + (size_t)(wave * 256 + i * 64) * 8);
  }
}

// ------------------------------- attention ----------------------------------
// 816 jobs: batch = blockIdx&7 (XCD pin), jj = blockIdx>>3 in 0..101 decodes
// (t desc from 31, n_t = ceil((t+1)/6) chunks). Block = 64 q-rows, 4 waves.
// Chunk sequence per kb: K0..K3,V0..V3. Chunk a -> buf a&3; 2 chunks always
// in flight (issue a+2 during compute of a; steady wait = vmcnt(8)).
__global__ __launch_bounds__(256, 2) void attn_kernel(
    const bf16_t* __restrict__ qg, const bf16_t* __restrict__ kg,
    const bf16_t* __restrict__ vTg, float* __restrict__ out,
    bf16_t* __restrict__ Opart, float* __restrict__ msum, float* __restrict__ lsum) {
  __shared__ __align__(16) bf16_t Pipe[4][8192];       // 64KB quad buffer
  __shared__ __align__(16) bf16_t Plds[4][16 * XSTR];  // 9.2KB per-wave P

  int bid = blockIdx.x;
  int b = bid & 7, jj = bid >> 3;
  int t = 31, base = 0, n = 6;
  for (;;) {
    int nt_ = (t + 6) / 6;
    if (jj < base + nt_) { n = nt_; break; }
    base += nt_; --t;
  }
  int c = jj - base;
  int kbs = t + 1;
  int csz = (kbs + n - 1) / n;
  int kb_lo = c * csz;
  int kb_hi = min(kbs, kb_lo + csz);
  int q0 = t * 64;

  int tid = threadIdx.x;
  int wave = tid >> 6, lane = tid & 63, lhi = lane >> 4, llo = lane & 15;
  bf16_t* Pb = &Plds[wave][0];

  const bf16_t* kbase = kg + ((size_t)b << 11) * 512;
  const bf16_t* vbase = vTg + ((size_t)b << 9) * 2048;

  int bc = 0;  // compute buffer (chunk a -> a&3)
  int ib = 2;  // next issue buffer
  issueK(kbase, kb_lo * 64, 0, &Pipe[0][0], wave, lane);
  issueK(kbase, kb_lo * 64, 1, &Pipe[1][0], wave, lane);

  // Q fragments (A-layout m=llo, k=lhi*8+j), rows q0+wave*16+llo, all 512 d
  const bf16_t* qrowp = qg + (size_t)((b << 11) + q0 + wave * 16 + llo) * 512;
  bf16x8 qf[16];
#pragma unroll
  for (int kk = 0; kk < 16; ++kk)
    qf[kk] = *(const bf16x8*)(qrowp + kk * 32 + lhi * 8);

  f32x4 Of[32];
#pragma unroll
  for (int i = 0; i < 32; ++i) Of[i] = (f32x4){0.f, 0.f, 0.f, 0.f};
  float m_i[4] = {-INFINITY, -INFINITY, -INFINITY, -INFINITY};
  float l_i[4] = {0.f, 0.f, 0.f, 0.f};

  for (int kb = kb_lo; kb < kb_hi; ++kb) {
    int key0 = kb * 64;
    bool more = (kb + 1 < kb_hi);
    f32x4 sf[4];
#pragma unroll
    for (int nt = 0; nt < 4; ++nt) sf[nt] = (f32x4){0.f, 0.f, 0.f, 0.f};

    // ---- QK: 4 K-chunks of 128 d; issue chunk a+2 (K2,K3,V0,V1) ----
#pragma unroll
    for (int cd = 0; cd < 4; ++cd) {
      if (cd < 2) issueK(kbase, key0, cd + 2, &Pipe[ib][0], wave, lane);
      else        issueV(vbase, key0, cd - 2, &Pipe[ib][0], wave, lane);
      ib = (ib + 1) & 3;
      PIPE_VM8;
      const bf16_t* bufc = &Pipe[bc][0];
      __builtin_amdgcn_s_setprio(1);
#pragma unroll
      for (int kkl = 0; kkl < 4; ++kkl) {
#pragma unroll
        for (int nt = 0; nt < 4; ++nt) {
          bf16x8 kf = *(const bf16x8*)(bufc + (nt * 16 + llo) * 128 +
                                       (((kkl * 4 + lhi) ^ (llo & 7)) * 8));
          sf[nt] = MFMA16(qf[cd * 4 + kkl], kf, sf[nt]);
        }
      }
      __builtin_amdgcn_s_setprio(0);
      bc = (bc + 1) & 3;
    }

    // ---- softmax (V0/V1 DMA in flight underneath) ----
    if (kb == t) {  // diagonal block: causal mask
#pragma unroll
      for (int nt = 0; nt < 4; ++nt) {
        int kloc = nt * 16 + llo;
#pragma unroll
        for (int r = 0; r < 4; ++r)
          if (kloc > wave * 16 + lhi * 4 + r) sf[nt][r] = -INFINITY;
      }
    }
    float vm[4];
#pragma unroll
    for (int r = 0; r < 4; ++r) {
      vm[r] = fmaxf(fmaxf(sf[0][r], sf[1][r]), fmaxf(sf[2][r], sf[3][r]));
      vm[r] = fmaxf(vm[r], __shfl_xor(vm[r], 1, 64));
      vm[r] = fmaxf(vm[r], __shfl_xor(vm[r], 2, 64));
      vm[r] = fmaxf(vm[r], __shfl_xor(vm[r], 4, 64));
      vm[r] = fmaxf(vm[r], __shfl_xor(vm[r], 8, 64));
    }
    float alpha[4];
    int resc = 0;
#pragma unroll
    for (int r = 0; r < 4; ++r) {
      float mn = fmaxf(m_i[r], vm[r]);
      alpha[r] = __expf(m_i[r] - mn);
      m_i[r] = mn;
      resc |= (alpha[r] < 1.0f) ? 1 : 0;
    }
#pragma unroll
    for (int r = 0; r < 4; ++r) {
      float ps = 0.f;
#pragma unroll
      for (int nt = 0; nt < 4; ++nt) {
        float p = __expf(sf[nt][r] - m_i[r]);
        ps += p;
        Pb[(lhi * 4 + r) * XSTR + nt * 16 + llo] = (bf16_t)p;
      }
      l_i[r] = alpha[r] * l_i[r] + ps;
    }
    if (__any(resc)) {
#pragma unroll
      for (int i = 0; i < 32; ++i)
#pragma unroll
        for (int r = 0; r < 4; ++r) Of[i][r] *= alpha[r];
    }

    // ---- PV: 4 V-chunks of 128 d; issue V2,V3, then next kb's K0,K1 ----
#pragma unroll
    for (int cv = 0; cv < 4; ++cv) {
      if (cv < 2) {
        issueV(vbase, key0, cv + 2, &Pipe[ib][0], wave, lane);
        ib = (ib + 1) & 3;
        PIPE_VM8;
      } else if (more) {
        issueK(kbase, key0 + 64, cv - 2, &Pipe[ib][0], wave, lane);
        ib = (ib + 1) & 3;
        PIPE_VM8;
      } else if (cv == 2) {
        PIPE_VM4;
      } else {
        PIPE_VM0;
      }
      const bf16_t* bufc = &Pipe[bc][0];
      __builtin_amdgcn_s_setprio(1);
#pragma unroll
      for (int ks = 0; ks < 2; ++ks) {
        bf16x8 pa = *(const bf16x8*)(&Pb[llo * XSTR + ks * 32 + lhi * 8]);
#pragma unroll
        for (int ntl = 0; ntl < 8; ++ntl) {
          bf16x8 bv = *(const bf16x8*)(bufc + (ntl * 16 + llo) * 64 +
                                       (((ks * 4 + lhi) ^ (llo & 7)) * 8));
          Of[cv * 8 + ntl] = MFMA16(pa, bv, Of[cv * 8 + ntl]);
        }
      }
      __builtin_amdgcn_s_setprio(0);
      bc = (bc + 1) & 3;
    }
  }  // kb loop

  // l reduction across the 16 col-lanes
#pragma unroll
  for (int r = 0; r < 4; ++r) {
    l_i[r] += __shfl_xor(l_i[r], 1, 64);
    l_i[r] += __shfl_xor(l_i[r], 2, 64);
    l_i[r] += __shfl_xor(l_i[r], 4, 64);
    l_i[r] += __shfl_xor(l_i[r], 8, 64);
  }

  // Of[i] holds d-col = (i>>3)*128 + (i&7)*16 + llo
  if (n == 1) {
    float linv[4];
#pragma unroll
    for (int r = 0; r < 4; ++r) linv[r] = 1.0f / l_i[r];
    float* ob = out + (size_t)((b << 11) + q0 + wave * 16) * 512;
#pragma unroll
    for (int i = 0; i < 32; ++i) {
      int dcol = ((i >> 3) << 7) + ((i & 7) << 4) + llo;
#pragma unroll
      for (int r = 0; r < 4; ++r)
        ob[(size_t)(lhi * 4 + r) * 512 + dcol] = Of[i][r] * linv[r];
    }
  } else {
    bf16_t* op = Opart + (size_t)bid * (64 * 512) + (size_t)(wave * 16) * 512;
#pragma unroll
    for (int i = 0; i < 32; ++i) {
      int dcol = ((i >> 3) << 7) + ((i & 7) << 4) + llo;
#pragma unroll
      for (int r = 0; r < 4; ++r)
        op[(size_t)(lhi * 4 + r) * 512 + dcol] = (bf16_t)Of[i][r];
    }
    if (llo == 0) {
#pragma unroll
      for (int r = 0; r < 4; ++r) {
        msum[bid * 64 + wave * 16 + lhi * 4 + r] = m_i[r];
        lsum[bid * 64 + wave * 16 + lhi * 4 + r] = l_i[r];
      }
    }
  }
}

// ------------------------------- merge --------------------------------------
// Combine 2-6 partials for tiles 6..31 of each batch.
__global__ __launch_bounds__(256) void merge_kernel(const bf16_t* __restrict__ Opart,
                                                    const float* __restrict__ msum,
                                                    const float* __restrict__ lsum,
                                                    float* __restrict__ out) {
  int idx = blockIdx.x * 256 + threadIdx.x;  // 8*26*64*512 = 6,815,744
  int d = idx & 511;
  int rg = idx >> 9;          // 0..13311 = b(8) x t(26) x row(64)
  int b = rg / 1664;
  int rr = rg - b * 1664;
  int t = 6 + (rr >> 6), row = rr & 63;
  int base = 0;
  for (int s = 31; s > t; --s) base += (s + 6) / 6;
  int n = (t + 6) / 6;
  float M = -INFINITY;
  for (int c2 = 0; c2 < n; ++c2)
    M = fmaxf(M, msum[((base + c2) * 8 + b) * 64 + row]);
  float denom = 0.f, acc = 0.f;
  for (int c2 = 0; c2 < n; ++c2) {
    int j = (base + c2) * 8 + b;
    float a = __expf(msum[j * 64 + row] - M);
    denom += a * lsum[j * 64 + row];
    acc += a * (float)Opart[(size_t)j * (64 * 512) + row * 512 + d];
  }
  out[(size_t)((b << 11) + (t << 6) + row) * 512 + d] = acc / denom;
}

// ------------------------------- launcher -----------------------------------
extern "C" void kernel_launch(void* const* d_in, const int* in_sizes, int n_in,
                              void* d_out, int out_size, void* d_ws, size_t ws_size,
                              hipStream_t stream) {
  (void)in_sizes; (void)n_in; (void)out_size; (void)ws_size;
  const float* x0 = (const float*)d_in[0];
  const float* x1 = (const float*)d_in[1];
  const float* x2 = (const float*)d_in[2];
  const float* Wq = (const float*)d_in[3];
  const float* bq = (const float*)d_in[4];
  const float* Wk = (const float*)d_in[5];
  const float* bk = (const float*)d_in[6];
  float* out = (float*)d_out;
  char* ws = (char*)d_ws;
  const size_t MB = 1ull << 20;
  bf16_t* Wtq = (bf16_t*)(ws + 0 * MB);             // 1 MB
  bf16_t* Wtk = (bf16_t*)(ws + 1 * MB);             // 1 MB
  bf16_t* qw  = (bf16_t*)(ws + 2 * MB);             // 16 MB
  bf16_t* kw  = (bf16_t*)(ws + 18 * MB);            // 16 MB
  bf16_t* vT  = (bf16_t*)(ws + 34 * MB);            // 16 MB
  float* msum = (float*)(ws + 50 * MB);             // 209 KB (816*64*4)
  float* lsum = (float*)(ws + 50 * MB + (512 << 10));
  bf16_t* Opart = (bf16_t*)(ws + 51 * MB);          // 53.5 MB (816*64*512*2)

  hipLaunchKernelGGL(wt_kernel, dim3(1024), dim3(256), 0, stream, Wq, Wk, Wtq, Wtk);
  hipLaunchKernelGGL(proj_kernel, dim3(1536), dim3(256), 0, stream,
                     x0, x1, x2, Wtq, Wtk, bq, bk, qw, kw, vT);
  hipLaunchKernelGGL(attn_kernel, dim3(816), dim3(256), 0, stream,
                     qw, kw, vT, out, Opart, msum, lsum);
  hipLaunchKernelGGL(merge_kernel, dim3(26624), dim3(256), 0, stream,
                     Opart, msum, lsum, out);
}

// Round 4
// 555.236 us; speedup vs baseline: 1.0217x; 1.0217x over previous
//
#include <hip/hip_runtime.h>
#include <hip/hip_bf16.h>
#include <math.h>

// ---------------------------------------------------------------------------
// DotScaledAttention: q=(x0@Wq+bq)/sqrt(512); k=x1@Wk+bk; v=x2@Wk+bk;
// out = causal_softmax(q k^T) v.   B=8 N=2048 d_emb=1024 d_red=512, fp32 io.
// R4: proj 128x128 tiles + XCD-group swizzle (FETCH 808->130MB).
// R5: proj K-loop software pipeline (prefetch to regs under MFMA phase).
// R6 (REVERTED): deeper DMA pipeline + setprio regressed 193->225us.
// R7: fat 32KB chunks (2 x 16KB sub-chunks), double buffer, issue-AFTER-
// barrier (WAR-safe with 2 bufs), vmcnt(0)+barrier once per fat phase.
// Sync events per kb-iter halve (8->4); per-phase compute doubles (32 MFMA)
// so prefetch flight time stays one full phase. No setprio (lockstep waves).
// ---------------------------------------------------------------------------

typedef __bf16 bf16_t;
typedef __attribute__((ext_vector_type(8))) __bf16 bf16x8;
typedef __attribute__((ext_vector_type(4))) __bf16 bf16x4;
typedef __attribute__((ext_vector_type(4))) float f32x4;

#define MFMA16(a, b, c) __builtin_amdgcn_mfma_f32_16x16x32_bf16((a), (b), (c), 0, 0, 0)

#define XSTR 72  // LDS row stride (bf16 elems), 144B = 16B-aligned

__device__ __forceinline__ void stage16(const void* g, void* l) {
  // async global->LDS DMA, 16B per lane; LDS dest = wave-uniform base + lane*16
  __builtin_amdgcn_global_load_lds(
      (__attribute__((address_space(1))) void*)(uintptr_t)g,
      (__attribute__((address_space(3))) void*)l, 16, 0, 0);
}

// attn fat-phase sync: drain own DMA (issued one full phase ago -> residual
// ~0), then block barrier. Issue of the NEXT fat chunk happens AFTER this
// barrier, so 2 buffers suffice (no WAR window).
#define PHASE_SYNC                              \
  {                                             \
    asm volatile("" ::: "memory");              \
    __builtin_amdgcn_s_waitcnt(0x0F70);         \
    __builtin_amdgcn_s_barrier();               \
    asm volatile("" ::: "memory");              \
  }

// proj barriers: A = ds_write visibility (lgkm drain only, no vmcnt drain);
// B = write-after-read protection, sched_barrier(0) pins MFMA above and the
// prefetch-consuming cvt/ds_write below, so the vmcnt wait lands post-MFMA.
#define PROJ_BAR_A                                    \
  {                                                   \
    asm volatile("s_waitcnt lgkmcnt(0)" ::: "memory"); \
    __builtin_amdgcn_s_barrier();                     \
    asm volatile("" ::: "memory");                    \
  }
#define PROJ_BAR_B                                    \
  {                                                   \
    __builtin_amdgcn_sched_barrier(0);                \
    __builtin_amdgcn_s_barrier();                     \
    asm volatile("" ::: "memory");                    \
  }

// --------------------------- W transpose + convert --------------------------
__global__ __launch_bounds__(256) void wt_kernel(const float* __restrict__ Wq,
                                                 const float* __restrict__ Wk,
                                                 bf16_t* __restrict__ Wtq,
                                                 bf16_t* __restrict__ Wtk) {
  __shared__ float tile[32][33];
  int bid = blockIdx.x;
  int mat = bid >> 9;
  int rem = bid & 511;
  int kt = rem >> 4, nt = rem & 15;
  int k0 = kt * 32, n0 = nt * 32;
  const float* src = mat ? Wk : Wq;
  bf16_t* dst = mat ? Wtk : Wtq;
  int t = threadIdx.x;
  int r = t >> 3, c4 = (t & 7) * 4;
  float4 v = *(const float4*)(src + (k0 + r) * 512 + n0 + c4);
  tile[r][c4 + 0] = v.x; tile[r][c4 + 1] = v.y;
  tile[r][c4 + 2] = v.z; tile[r][c4 + 3] = v.w;
  __syncthreads();
  bf16x4 o;
  o[0] = (bf16_t)tile[c4 + 0][r];
  o[1] = (bf16_t)tile[c4 + 1][r];
  o[2] = (bf16_t)tile[c4 + 2][r];
  o[3] = (bf16_t)tile[c4 + 3][r];
  *(bf16x4*)(dst + (n0 + r) * 1024 + k0 + c4) = o;
}

// ------------------------------- projections --------------------------------
// 128x128 output tile per block. Grid = 1536 = 3 mats x 128 mblk x 4 nblk.
// Swizzle: xcd = bid&7; i = bid>>3; nblk = i&3; g = (i>>2)*8 + xcd;
// mat = g>>7; mblk = g&127.  The 4 nblk jobs of a (mat,mblk) group are
// consecutive on one XCD -> the 512KB x-slab is fetched from HBM once and
// served 3x from that XCD's L2.
__global__ __launch_bounds__(256, 3) void proj_kernel(
    const float* __restrict__ x0, const float* __restrict__ x1, const float* __restrict__ x2,
    const bf16_t* __restrict__ Wtq, const bf16_t* __restrict__ Wtk,
    const float* __restrict__ bq, const float* __restrict__ bk,
    bf16_t* __restrict__ qo, bf16_t* __restrict__ ko, bf16_t* __restrict__ vT) {
  __shared__ __align__(16) bf16_t Xs[128 * XSTR];
  __shared__ __align__(16) bf16_t Ws[128 * XSTR];
  int bid = blockIdx.x;
  int xcd = bid & 7;
  int i5 = bid >> 3;           // 0..191
  int nblk = i5 & 3;           // 0..3  (128-wide output column tile)
  int g = (i5 >> 2) * 8 + xcd; // 0..383 bijective
  int mat = g >> 7;            // 0..2
  int mblk = g & 127;          // 0..127
  const float* xsrc = (mat == 0) ? x0 : ((mat == 1) ? x1 : x2);
  const bf16_t* wsrc = (mat == 0) ? Wtq : Wtk;
  int tid = threadIdx.x;
  int wave = tid >> 6, lane = tid & 63, lhi = lane >> 4, llo = lane & 15;

  f32x4 acc[2][8];
#pragma unroll
  for (int i = 0; i < 2; ++i)
#pragma unroll
    for (int j = 0; j < 8; ++j) acc[i][j] = (f32x4){0.f, 0.f, 0.f, 0.f};

  int xrow = tid >> 1, xseg = tid & 1;   // 128 rows x 2 segs of 32 K-elems
  int wrow = tid >> 1, wseg = tid & 1;
  const float* xbase = xsrc + (size_t)(mblk * 128 + xrow) * 1024 + xseg * 32;
  const bf16_t* wbase = wsrc + (size_t)(nblk * 128 + wrow) * 1024 + wseg * 32;

  // prefetch registers (kt+1's data lives here during kt's MFMA phase)
  float4 nx[8];
  bf16x8 nw[4];

  // prologue: load kt=0 and stage to LDS
#pragma unroll
  for (int i = 0; i < 8; ++i) nx[i] = *(const float4*)(xbase + i * 4);
#pragma unroll
  for (int i = 0; i < 4; ++i) nw[i] = *(const bf16x8*)(wbase + i * 8);
  {
    bf16_t tmp[32];
#pragma unroll
    for (int i = 0; i < 8; ++i) {
      tmp[i * 4 + 0] = (bf16_t)nx[i].x; tmp[i * 4 + 1] = (bf16_t)nx[i].y;
      tmp[i * 4 + 2] = (bf16_t)nx[i].z; tmp[i * 4 + 3] = (bf16_t)nx[i].w;
    }
#pragma unroll
    for (int i = 0; i < 4; ++i)
      *(bf16x8*)(&Xs[xrow * XSTR + xseg * 32 + i * 8]) = *(bf16x8*)(&tmp[i * 8]);
#pragma unroll
    for (int i = 0; i < 4; ++i)
      *(bf16x8*)(&Ws[wrow * XSTR + wseg * 32 + i * 8]) = nw[i];
  }

  for (int kt = 0; kt < 16; ++kt) {
    PROJ_BAR_A;  // ds_writes visible; prefetch loads NOT drained
    if (kt < 15) {
      int k0 = (kt + 1) * 64;
#pragma unroll
      for (int i = 0; i < 8; ++i) nx[i] = *(const float4*)(xbase + k0 + i * 4);
#pragma unroll
      for (int i = 0; i < 4; ++i) nw[i] = *(const bf16x8*)(wbase + k0 + i * 8);
    }
    // MFMA phase on the current LDS tile (loads in flight underneath)
#pragma unroll
    for (int ks = 0; ks < 2; ++ks) {
      bf16x8 af[2], bfr[8];
#pragma unroll
      for (int mt = 0; mt < 2; ++mt)
        af[mt] = *(const bf16x8*)(&Xs[(wave * 32 + mt * 16 + llo) * XSTR + ks * 32 + lhi * 8]);
#pragma unroll
      for (int nt = 0; nt < 8; ++nt)
        bfr[nt] = *(const bf16x8*)(&Ws[(nt * 16 + llo) * XSTR + ks * 32 + lhi * 8]);
#pragma unroll
      for (int mt = 0; mt < 2; ++mt)
#pragma unroll
        for (int nt = 0; nt < 8; ++nt)
          acc[mt][nt] = MFMA16(af[mt], bfr[nt], acc[mt][nt]);
    }
    if (kt < 15) {
      PROJ_BAR_B;  // reads done; vmcnt wait for nx/nw lands HERE, post-MFMA
      bf16_t tmp[32];
#pragma unroll
      for (int i = 0; i < 8; ++i) {
        tmp[i * 4 + 0] = (bf16_t)nx[i].x; tmp[i * 4 + 1] = (bf16_t)nx[i].y;
        tmp[i * 4 + 2] = (bf16_t)nx[i].z; tmp[i * 4 + 3] = (bf16_t)nx[i].w;
      }
#pragma unroll
      for (int i = 0; i < 4; ++i)
        *(bf16x8*)(&Xs[xrow * XSTR + xseg * 32 + i * 8]) = *(bf16x8*)(&tmp[i * 8]);
#pragma unroll
      for (int i = 0; i < 4; ++i)
        *(bf16x8*)(&Ws[wrow * XSTR + wseg * 32 + i * 8]) = nw[i];
    }
  }

  const float* bias = (mat == 0) ? bq : bk;
  float scale = (mat == 0) ? 0.044194173824159216f : 1.0f;  // 1/sqrt(512)
#pragma unroll
  for (int mt = 0; mt < 2; ++mt) {
#pragma unroll
    for (int nt = 0; nt < 8; ++nt) {
      int n = nblk * 128 + nt * 16 + llo;
      float bv = bias[n];
      int rowb = mblk * 128 + wave * 32 + mt * 16 + lhi * 4;
      float vals[4];
#pragma unroll
      for (int r = 0; r < 4; ++r) vals[r] = (acc[mt][nt][r] + bv) * scale;
      if (mat == 0) {
#pragma unroll
        for (int r = 0; r < 4; ++r) qo[(size_t)(rowb + r) * 512 + n] = (bf16_t)vals[r];
      } else if (mat == 1) {
#pragma unroll
        for (int r = 0; r < 4; ++r) ko[(size_t)(rowb + r) * 512 + n] = (bf16_t)vals[r];
      } else {
        int batch = rowb >> 11, tok = rowb & 2047;
        bf16x4 o;
        o[0] = (bf16_t)vals[0]; o[1] = (bf16_t)vals[1];
        o[2] = (bf16_t)vals[2]; o[3] = (bf16_t)vals[3];
        *(bf16x4*)(vT + (size_t)(batch * 512 + n) * 2048 + tok) = o;
      }
    }
  }
}

// ------------------------- attention: staging helpers ------------------------
// K sub-chunk: 64 keys x 128 d (d-range cd*128..) -> 16KB.
// granule idx: key = idx>>4, physical seg p = idx&15, logical seg s = p^(key&7)
__device__ __forceinline__ void issueK(const bf16_t* kbase, int key0, int cd,
                                       bf16_t* buf, int wave, int lane) {
#pragma unroll
  for (int i = 0; i < 4; ++i) {
    int idx = wave * 256 + i * 64 + lane;
    int key = idx >> 4, p = idx & 15;
    int s = p ^ (key & 7);
    stage16(kbase + (size_t)(key0 + key) * 512 + cd * 128 + s * 8,
            buf + (size_t)(wave * 256 + i * 64) * 8);
  }
}
// V sub-chunk: 128 d (cv*128..) x 64 keys -> 16KB.
// granule idx: dl = idx>>3, p = idx&7, s = p^(dl&7)
__device__ __forceinline__ void issueV(const bf16_t* vbase, int key0, int cv,
                                       bf16_t* buf, int wave, int lane) {
#pragma unroll
  for (int i = 0; i < 4; ++i) {
    int idx = wave * 256 + i * 64 + lane;
    int dl = idx >> 3, p = idx & 7;
    int s = p ^ (dl & 7);
    stage16(vbase + (size_t)(cv * 128 + dl) * 2048 + key0 + s * 8,
            buf + (size_t)(wave * 256 + i * 64) * 8);
  }
}

// ------------------------------- attention ----------------------------------
// 816 jobs: batch = blockIdx&7 (XCD pin), jj = blockIdx>>3 in 0..101 decodes
// (t desc from 31, n_t = ceil((t+1)/6) chunks). Block = 64 q-rows, 4 waves.
// Per kb: 4 fat phases {K(d0..255), K(d256..511), V(d0..255), V(d256..511)},
// each = 32KB staged as 2 sub-chunks. 2 fat buffers, parity p; the next fat
// chunk is issued AFTER the phase barrier (WAR-safe), drained by the NEXT
// phase's vmcnt(0) after one full phase of flight time.
__global__ __launch_bounds__(256, 2) void attn_kernel(
    const bf16_t* __restrict__ qg, const bf16_t* __restrict__ kg,
    const bf16_t* __restrict__ vTg, float* __restrict__ out,
    bf16_t* __restrict__ Opart, float* __restrict__ msum, float* __restrict__ lsum) {
  __shared__ __align__(16) bf16_t Pipe[2][16384];      // 64KB double fat buffer
  __shared__ __align__(16) bf16_t Plds[4][16 * XSTR];  // 9.2KB per-wave P

  int bid = blockIdx.x;
  int b = bid & 7, jj = bid >> 3;
  int t = 31, base = 0, n = 6;
  for (;;) {
    int nt_ = (t + 6) / 6;
    if (jj < base + nt_) { n = nt_; break; }
    base += nt_; --t;
  }
  int c = jj - base;
  int kbs = t + 1;
  int csz = (kbs + n - 1) / n;
  int kb_lo = c * csz;
  int kb_hi = min(kbs, kb_lo + csz);
  int q0 = t * 64;

  int tid = threadIdx.x;
  int wave = tid >> 6, lane = tid & 63, lhi = lane >> 4, llo = lane & 15;
  bf16_t* Pb = &Plds[wave][0];

  const bf16_t* kbase = kg + ((size_t)b << 11) * 512;
  const bf16_t* vbase = vTg + ((size_t)b << 9) * 2048;

  int p = 0;
  // prologue: fat K chunk (d 0..255) of first kb
  issueK(kbase, kb_lo * 64, 0, &Pipe[0][0], wave, lane);
  issueK(kbase, kb_lo * 64, 1, &Pipe[0][8192], wave, lane);

  // Q fragments (A-layout m=llo, k=lhi*8+j), rows q0+wave*16+llo, all 512 d
  const bf16_t* qrowp = qg + (size_t)((b << 11) + q0 + wave * 16 + llo) * 512;
  bf16x8 qf[16];
#pragma unroll
  for (int kk = 0; kk < 16; ++kk)
    qf[kk] = *(const bf16x8*)(qrowp + kk * 32 + lhi * 8);

  f32x4 Of[32];
#pragma unroll
  for (int i = 0; i < 32; ++i) Of[i] = (f32x4){0.f, 0.f, 0.f, 0.f};
  float m_i[4] = {-INFINITY, -INFINITY, -INFINITY, -INFINITY};
  float l_i[4] = {0.f, 0.f, 0.f, 0.f};

  for (int kb = kb_lo; kb < kb_hi; ++kb) {
    int key0 = kb * 64;
    bool more = (kb + 1 < kb_hi);
    f32x4 sf[4];
#pragma unroll
    for (int nt = 0; nt < 4; ++nt) sf[nt] = (f32x4){0.f, 0.f, 0.f, 0.f};

    // ---- QK: 2 fat phases (d 0..255, d 256..511) ----
#pragma unroll
    for (int h = 0; h < 2; ++h) {
      PHASE_SYNC;  // drain this phase's fat chunk; block barrier
      if (h == 0) {
        issueK(kbase, key0, 2, &Pipe[p ^ 1][0], wave, lane);
        issueK(kbase, key0, 3, &Pipe[p ^ 1][8192], wave, lane);
      } else {
        issueV(vbase, key0, 0, &Pipe[p ^ 1][0], wave, lane);
        issueV(vbase, key0, 1, &Pipe[p ^ 1][8192], wave, lane);
      }
#pragma unroll
      for (int sub = 0; sub < 2; ++sub) {
        const bf16_t* bufc = &Pipe[p][sub * 8192];
        int cd = h * 2 + sub;
#pragma unroll
        for (int kkl = 0; kkl < 4; ++kkl) {
#pragma unroll
          for (int nt = 0; nt < 4; ++nt) {
            bf16x8 kf = *(const bf16x8*)(bufc + (nt * 16 + llo) * 128 +
                                         (((kkl * 4 + lhi) ^ (llo & 7)) * 8));
            sf[nt] = MFMA16(qf[cd * 4 + kkl], kf, sf[nt]);
          }
        }
      }
      p ^= 1;
    }

    // ---- softmax (V0/V1 fat chunk in flight underneath) ----
    if (kb == t) {  // diagonal block: causal mask
#pragma unroll
      for (int nt = 0; nt < 4; ++nt) {
        int kloc = nt * 16 + llo;
#pragma unroll
        for (int r = 0; r < 4; ++r)
          if (kloc > wave * 16 + lhi * 4 + r) sf[nt][r] = -INFINITY;
      }
    }
    float vm[4];
#pragma unroll
    for (int r = 0; r < 4; ++r) {
      vm[r] = fmaxf(fmaxf(sf[0][r], sf[1][r]), fmaxf(sf[2][r], sf[3][r]));
      vm[r] = fmaxf(vm[r], __shfl_xor(vm[r], 1, 64));
      vm[r] = fmaxf(vm[r], __shfl_xor(vm[r], 2, 64));
      vm[r] = fmaxf(vm[r], __shfl_xor(vm[r], 4, 64));
      vm[r] = fmaxf(vm[r], __shfl_xor(vm[r], 8, 64));
    }
    float alpha[4];
    int resc = 0;
#pragma unroll
    for (int r = 0; r < 4; ++r) {
      float mn = fmaxf(m_i[r], vm[r]);
      alpha[r] = __expf(m_i[r] - mn);
      m_i[r] = mn;
      resc |= (alpha[r] < 1.0f) ? 1 : 0;
    }
#pragma unroll
    for (int r = 0; r < 4; ++r) {
      float ps = 0.f;
#pragma unroll
      for (int nt = 0; nt < 4; ++nt) {
        float p2 = __expf(sf[nt][r] - m_i[r]);
        ps += p2;
        Pb[(lhi * 4 + r) * XSTR + nt * 16 + llo] = (bf16_t)p2;
      }
      l_i[r] = alpha[r] * l_i[r] + ps;
    }
    if (__any(resc)) {
#pragma unroll
      for (int i = 0; i < 32; ++i)
#pragma unroll
        for (int r = 0; r < 4; ++r) Of[i][r] *= alpha[r];
    }

    // ---- PV: 2 fat phases (d 0..255, d 256..511) ----
#pragma unroll
    for (int h = 0; h < 2; ++h) {
      PHASE_SYNC;
      if (h == 0) {
        issueV(vbase, key0, 2, &Pipe[p ^ 1][0], wave, lane);
        issueV(vbase, key0, 3, &Pipe[p ^ 1][8192], wave, lane);
      } else if (more) {
        issueK(kbase, key0 + 64, 0, &Pipe[p ^ 1][0], wave, lane);
        issueK(kbase, key0 + 64, 1, &Pipe[p ^ 1][8192], wave, lane);
      }
#pragma unroll
      for (int sub = 0; sub < 2; ++sub) {
        const bf16_t* bufc = &Pipe[p][sub * 8192];
        int cv = h * 2 + sub;
#pragma unroll
        for (int ks = 0; ks < 2; ++ks) {
          bf16x8 pa = *(const bf16x8*)(&Pb[llo * XSTR + ks * 32 + lhi * 8]);
#pragma unroll
          for (int ntl = 0; ntl < 8; ++ntl) {
            bf16x8 bv = *(const bf16x8*)(bufc + (ntl * 16 + llo) * 64 +
                                         (((ks * 4 + lhi) ^ (llo & 7)) * 8));
            Of[cv * 8 + ntl] = MFMA16(pa, bv, Of[cv * 8 + ntl]);
          }
        }
      }
      p ^= 1;
    }
  }  // kb loop

  // l reduction across the 16 col-lanes
#pragma unroll
  for (int r = 0; r < 4; ++r) {
    l_i[r] += __shfl_xor(l_i[r], 1, 64);
    l_i[r] += __shfl_xor(l_i[r], 2, 64);
    l_i[r] += __shfl_xor(l_i[r], 4, 64);
    l_i[r] += __shfl_xor(l_i[r], 8, 64);
  }

  // Of[i] holds d-col = (i>>3)*128 + (i&7)*16 + llo
  if (n == 1) {
    float linv[4];
#pragma unroll
    for (int r = 0; r < 4; ++r) linv[r] = 1.0f / l_i[r];
    float* ob = out + (size_t)((b << 11) + q0 + wave * 16) * 512;
#pragma unroll
    for (int i = 0; i < 32; ++i) {
      int dcol = ((i >> 3) << 7) + ((i & 7) << 4) + llo;
#pragma unroll
      for (int r = 0; r < 4; ++r)
        ob[(size_t)(lhi * 4 + r) * 512 + dcol] = Of[i][r] * linv[r];
    }
  } else {
    bf16_t* op = Opart + (size_t)bid * (64 * 512) + (size_t)(wave * 16) * 512;
#pragma unroll
    for (int i = 0; i < 32; ++i) {
      int dcol = ((i >> 3) << 7) + ((i & 7) << 4) + llo;
#pragma unroll
      for (int r = 0; r < 4; ++r)
        op[(size_t)(lhi * 4 + r) * 512 + dcol] = (bf16_t)Of[i][r];
    }
    if (llo == 0) {
#pragma unroll
      for (int r = 0; r < 4; ++r) {
        msum[bid * 64 + wave * 16 + lhi * 4 + r] = m_i[r];
        lsum[bid * 64 + wave * 16 + lhi * 4 + r] = l_i[r];
      }
    }
  }
}

// ------------------------------- merge --------------------------------------
// Combine 2-6 partials for tiles 6..31 of each batch.
__global__ __launch_bounds__(256) void merge_kernel(const bf16_t* __restrict__ Opart,
                                                    const float* __restrict__ msum,
                                                    const float* __restrict__ lsum,
                                                    float* __restrict__ out) {
  int idx = blockIdx.x * 256 + threadIdx.x;  // 8*26*64*512 = 6,815,744
  int d = idx & 511;
  int rg = idx >> 9;          // 0..13311 = b(8) x t(26) x row(64)
  int b = rg / 1664;
  int rr = rg - b * 1664;
  int t = 6 + (rr >> 6), row = rr & 63;
  int base = 0;
  for (int s = 31; s > t; --s) base += (s + 6) / 6;
  int n = (t + 6) / 6;
  float M = -INFINITY;
  for (int c2 = 0; c2 < n; ++c2)
    M = fmaxf(M, msum[((base + c2) * 8 + b) * 64 + row]);
  float denom = 0.f, acc = 0.f;
  for (int c2 = 0; c2 < n; ++c2) {
    int j = (base + c2) * 8 + b;
    float a = __expf(msum[j * 64 + row] - M);
    denom += a * lsum[j * 64 + row];
    acc += a * (float)Opart[(size_t)j * (64 * 512) + row * 512 + d];
  }
  out[(size_t)((b << 11) + (t << 6) + row) * 512 + d] = acc / denom;
}

// ------------------------------- launcher -----------------------------------
extern "C" void kernel_launch(void* const* d_in, const int* in_sizes, int n_in,
                              void* d_out, int out_size, void* d_ws, size_t ws_size,
                              hipStream_t stream) {
  (void)in_sizes; (void)n_in; (void)out_size; (void)ws_size;
  const float* x0 = (const float*)d_in[0];
  const float* x1 = (const float*)d_in[1];
  const float* x2 = (const float*)d_in[2];
  const float* Wq = (const float*)d_in[3];
  const float* bq = (const float*)d_in[4];
  const float* Wk = (const float*)d_in[5];
  const float* bk = (const float*)d_in[6];
  float* out = (float*)d_out;
  char* ws = (char*)d_ws;
  const size_t MB = 1ull << 20;
  bf16_t* Wtq = (bf16_t*)(ws + 0 * MB);             // 1 MB
  bf16_t* Wtk = (bf16_t*)(ws + 1 * MB);             // 1 MB
  bf16_t* qw  = (bf16_t*)(ws + 2 * MB);             // 16 MB
  bf16_t* kw  = (bf16_t*)(ws + 18 * MB);            // 16 MB
  bf16_t* vT  = (bf16_t*)(ws + 34 * MB);            // 16 MB
  float* msum = (float*)(ws + 50 * MB);             // 209 KB (816*64*4)
  float* lsum = (float*)(ws + 50 * MB + (512 << 10));
  bf16_t* Opart = (bf16_t*)(ws + 51 * MB);          // 53.5 MB (816*64*512*2)

  hipLaunchKernelGGL(wt_kernel, dim3(1024), dim3(256), 0, stream, Wq, Wk, Wtq, Wtk);
  hipLaunchKernelGGL(proj_kernel, dim3(1536), dim3(256), 0, stream,
                     x0, x1, x2, Wtq, Wtk, bq, bk, qw, kw, vT);
  hipLaunchKernelGGL(attn_kernel, dim3(816), dim3(256), 0, stream,
                     qw, kw, vT, out, Opart, msum, lsum);
  hipLaunchKernelGGL(merge_kernel, dim3(26624), dim3(256), 0, stream,
                     Opart, msum, lsum, out);
}

// Round 6
// 526.961 us; speedup vs baseline: 1.0765x; 1.0537x over previous
//
#include <hip/hip_runtime.h>
#include <hip/hip_bf16.h>
#include <math.h>

// ---------------------------------------------------------------------------
// DotScaledAttention: q=(x0@Wq+bq)/sqrt(512); k=x1@Wk+bk; v=x2@Wk+bk;
// out = causal_softmax(q k^T) v.   B=8 N=2048 d_emb=1024 d_red=512, fp32 io.
// R4: proj 128x128 tiles + XCD-group swizzle (FETCH 808->130MB).
// R5: proj K-loop software pipeline (prefetch to regs under MFMA phase).
// R6 (REVERTED): depth-3 + setprio, 225us. R7 (REVERTED): fat 32KB, 205us.
// R8: TLP attack. 8KB chunks (64keys x 64d), tri-buffer 24KB + P 9.2KB =
// 33.8KB LDS -> 4 blocks/CU by LDS (was 2); all 816 blocks resident (no
// tail). R3's proven issue-1-ahead + counted vmcnt(2) wait. Nontemporal
// Opart/out stores so the batch-pinned XCD L2 retains K/V.
// R8b: identical resubmit (previous run died on container acquire, not
// on the kernel; audit found no hang path).
// ---------------------------------------------------------------------------

typedef __bf16 bf16_t;
typedef __attribute__((ext_vector_type(8))) __bf16 bf16x8;
typedef __attribute__((ext_vector_type(4))) __bf16 bf16x4;
typedef __attribute__((ext_vector_type(4))) float f32x4;

#define MFMA16(a, b, c) __builtin_amdgcn_mfma_f32_16x16x32_bf16((a), (b), (c), 0, 0, 0)

#define XSTR 72  // LDS row stride (bf16 elems), 144B = 16B-aligned

__device__ __forceinline__ void stage16(const void* g, void* l) {
  // async global->LDS DMA, 16B per lane; LDS dest = wave-uniform base + lane*16
  __builtin_amdgcn_global_load_lds(
      (__attribute__((address_space(1))) void*)(uintptr_t)g,
      (__attribute__((address_space(3))) void*)l, 16, 0, 0);
}

// attn pipeline sync. Each wave stages 2x16B per 8KB chunk; chunk i+1 is
// issued just before this wait, so outstanding = {chunk i (2), chunk i+1 (2)}.
// 0x0F72 = vmcnt(2): chunk i drained, chunk i+1 stays in flight.
#define PW_MORE                                 \
  {                                             \
    asm volatile("" ::: "memory");              \
    __builtin_amdgcn_s_waitcnt(0x0F72);         \
    __builtin_amdgcn_s_barrier();               \
    asm volatile("" ::: "memory");              \
  }
#define PW_LAST                                 \
  {                                             \
    asm volatile("" ::: "memory");              \
    __builtin_amdgcn_s_waitcnt(0x0F70);         \
    __builtin_amdgcn_s_barrier();               \
    asm volatile("" ::: "memory");              \
  }

// proj barriers: A = ds_write visibility (lgkm drain only, no vmcnt drain);
// B = write-after-read protection, sched_barrier(0) pins MFMA above and the
// prefetch-consuming cvt/ds_write below, so the vmcnt wait lands post-MFMA.
#define PROJ_BAR_A                                    \
  {                                                   \
    asm volatile("s_waitcnt lgkmcnt(0)" ::: "memory"); \
    __builtin_amdgcn_s_barrier();                     \
    asm volatile("" ::: "memory");                    \
  }
#define PROJ_BAR_B                                    \
  {                                                   \
    __builtin_amdgcn_sched_barrier(0);                \
    __builtin_amdgcn_s_barrier();                     \
    asm volatile("" ::: "memory");                    \
  }

// --------------------------- W transpose + convert --------------------------
__global__ __launch_bounds__(256) void wt_kernel(const float* __restrict__ Wq,
                                                 const float* __restrict__ Wk,
                                                 bf16_t* __restrict__ Wtq,
                                                 bf16_t* __restrict__ Wtk) {
  __shared__ float tile[32][33];
  int bid = blockIdx.x;
  int mat = bid >> 9;
  int rem = bid & 511;
  int kt = rem >> 4, nt = rem & 15;
  int k0 = kt * 32, n0 = nt * 32;
  const float* src = mat ? Wk : Wq;
  bf16_t* dst = mat ? Wtk : Wtq;
  int t = threadIdx.x;
  int r = t >> 3, c4 = (t & 7) * 4;
  float4 v = *(const float4*)(src + (k0 + r) * 512 + n0 + c4);
  tile[r][c4 + 0] = v.x; tile[r][c4 + 1] = v.y;
  tile[r][c4 + 2] = v.z; tile[r][c4 + 3] = v.w;
  __syncthreads();
  bf16x4 o;
  o[0] = (bf16_t)tile[c4 + 0][r];
  o[1] = (bf16_t)tile[c4 + 1][r];
  o[2] = (bf16_t)tile[c4 + 2][r];
  o[3] = (bf16_t)tile[c4 + 3][r];
  *(bf16x4*)(dst + (n0 + r) * 1024 + k0 + c4) = o;
}

// ------------------------------- projections --------------------------------
// 128x128 output tile per block. Grid = 1536 = 3 mats x 128 mblk x 4 nblk.
// Swizzle: xcd = bid&7; i = bid>>3; nblk = i&3; g = (i>>2)*8 + xcd;
// mat = g>>7; mblk = g&127.  The 4 nblk jobs of a (mat,mblk) group are
// consecutive on one XCD -> the 512KB x-slab is fetched from HBM once and
// served 3x from that XCD's L2.
__global__ __launch_bounds__(256, 3) void proj_kernel(
    const float* __restrict__ x0, const float* __restrict__ x1, const float* __restrict__ x2,
    const bf16_t* __restrict__ Wtq, const bf16_t* __restrict__ Wtk,
    const float* __restrict__ bq, const float* __restrict__ bk,
    bf16_t* __restrict__ qo, bf16_t* __restrict__ ko, bf16_t* __restrict__ vT) {
  __shared__ __align__(16) bf16_t Xs[128 * XSTR];
  __shared__ __align__(16) bf16_t Ws[128 * XSTR];
  int bid = blockIdx.x;
  int xcd = bid & 7;
  int i5 = bid >> 3;           // 0..191
  int nblk = i5 & 3;           // 0..3  (128-wide output column tile)
  int g = (i5 >> 2) * 8 + xcd; // 0..383 bijective
  int mat = g >> 7;            // 0..2
  int mblk = g & 127;          // 0..127
  const float* xsrc = (mat == 0) ? x0 : ((mat == 1) ? x1 : x2);
  const bf16_t* wsrc = (mat == 0) ? Wtq : Wtk;
  int tid = threadIdx.x;
  int wave = tid >> 6, lane = tid & 63, lhi = lane >> 4, llo = lane & 15;

  f32x4 acc[2][8];
#pragma unroll
  for (int i = 0; i < 2; ++i)
#pragma unroll
    for (int j = 0; j < 8; ++j) acc[i][j] = (f32x4){0.f, 0.f, 0.f, 0.f};

  int xrow = tid >> 1, xseg = tid & 1;   // 128 rows x 2 segs of 32 K-elems
  int wrow = tid >> 1, wseg = tid & 1;
  const float* xbase = xsrc + (size_t)(mblk * 128 + xrow) * 1024 + xseg * 32;
  const bf16_t* wbase = wsrc + (size_t)(nblk * 128 + wrow) * 1024 + wseg * 32;

  // prefetch registers (kt+1's data lives here during kt's MFMA phase)
  float4 nx[8];
  bf16x8 nw[4];

  // prologue: load kt=0 and stage to LDS
#pragma unroll
  for (int i = 0; i < 8; ++i) nx[i] = *(const float4*)(xbase + i * 4);
#pragma unroll
  for (int i = 0; i < 4; ++i) nw[i] = *(const bf16x8*)(wbase + i * 8);
  {
    bf16_t tmp[32];
#pragma unroll
    for (int i = 0; i < 8; ++i) {
      tmp[i * 4 + 0] = (bf16_t)nx[i].x; tmp[i * 4 + 1] = (bf16_t)nx[i].y;
      tmp[i * 4 + 2] = (bf16_t)nx[i].z; tmp[i * 4 + 3] = (bf16_t)nx[i].w;
    }
#pragma unroll
    for (int i = 0; i < 4; ++i)
      *(bf16x8*)(&Xs[xrow * XSTR + xseg * 32 + i * 8]) = *(bf16x8*)(&tmp[i * 8]);
#pragma unroll
    for (int i = 0; i < 4; ++i)
      *(bf16x8*)(&Ws[wrow * XSTR + wseg * 32 + i * 8]) = nw[i];
  }

  for (int kt = 0; kt < 16; ++kt) {
    PROJ_BAR_A;  // ds_writes visible; prefetch loads NOT drained
    if (kt < 15) {
      int k0 = (kt + 1) * 64;
#pragma unroll
      for (int i = 0; i < 8; ++i) nx[i] = *(const float4*)(xbase + k0 + i * 4);
#pragma unroll
      for (int i = 0; i < 4; ++i) nw[i] = *(const bf16x8*)(wbase + k0 + i * 8);
    }
    // MFMA phase on the current LDS tile (loads in flight underneath)
#pragma unroll
    for (int ks = 0; ks < 2; ++ks) {
      bf16x8 af[2], bfr[8];
#pragma unroll
      for (int mt = 0; mt < 2; ++mt)
        af[mt] = *(const bf16x8*)(&Xs[(wave * 32 + mt * 16 + llo) * XSTR + ks * 32 + lhi * 8]);
#pragma unroll
      for (int nt = 0; nt < 8; ++nt)
        bfr[nt] = *(const bf16x8*)(&Ws[(nt * 16 + llo) * XSTR + ks * 32 + lhi * 8]);
#pragma unroll
      for (int mt = 0; mt < 2; ++mt)
#pragma unroll
        for (int nt = 0; nt < 8; ++nt)
          acc[mt][nt] = MFMA16(af[mt], bfr[nt], acc[mt][nt]);
    }
    if (kt < 15) {
      PROJ_BAR_B;  // reads done; vmcnt wait for nx/nw lands HERE, post-MFMA
      bf16_t tmp[32];
#pragma unroll
      for (int i = 0; i < 8; ++i) {
        tmp[i * 4 + 0] = (bf16_t)nx[i].x; tmp[i * 4 + 1] = (bf16_t)nx[i].y;
        tmp[i * 4 + 2] = (bf16_t)nx[i].z; tmp[i * 4 + 3] = (bf16_t)nx[i].w;
      }
#pragma unroll
      for (int i = 0; i < 4; ++i)
        *(bf16x8*)(&Xs[xrow * XSTR + xseg * 32 + i * 8]) = *(bf16x8*)(&tmp[i * 8]);
#pragma unroll
      for (int i = 0; i < 4; ++i)
        *(bf16x8*)(&Ws[wrow * XSTR + wseg * 32 + i * 8]) = nw[i];
    }
  }

  const float* bias = (mat == 0) ? bq : bk;
  float scale = (mat == 0) ? 0.044194173824159216f : 1.0f;  // 1/sqrt(512)
#pragma unroll
  for (int mt = 0; mt < 2; ++mt) {
#pragma unroll
    for (int nt = 0; nt < 8; ++nt) {
      int n = nblk * 128 + nt * 16 + llo;
      float bv = bias[n];
      int rowb = mblk * 128 + wave * 32 + mt * 16 + lhi * 4;
      float vals[4];
#pragma unroll
      for (int r = 0; r < 4; ++r) vals[r] = (acc[mt][nt][r] + bv) * scale;
      if (mat == 0) {
#pragma unroll
        for (int r = 0; r < 4; ++r) qo[(size_t)(rowb + r) * 512 + n] = (bf16_t)vals[r];
      } else if (mat == 1) {
#pragma unroll
        for (int r = 0; r < 4; ++r) ko[(size_t)(rowb + r) * 512 + n] = (bf16_t)vals[r];
      } else {
        int batch = rowb >> 11, tok = rowb & 2047;
        bf16x4 o;
        o[0] = (bf16_t)vals[0]; o[1] = (bf16_t)vals[1];
        o[2] = (bf16_t)vals[2]; o[3] = (bf16_t)vals[3];
        *(bf16x4*)(vT + (size_t)(batch * 512 + n) * 2048 + tok) = o;
      }
    }
  }
}

// ------------------------- attention: staging helpers ------------------------
// K chunk: 64 keys x 64 d (d-range cd*64..) -> 8KB. 2 granules per lane.
// granule idx: key = idx>>3 (8 granules/row), p = idx&7, s = p^(key&7)
__device__ __forceinline__ void issueK8(const bf16_t* kbase, int key0, int cd,
                                        bf16_t* buf, int wave, int lane) {
#pragma unroll
  for (int i = 0; i < 2; ++i) {
    int idx = wave * 128 + i * 64 + lane;
    int key = idx >> 3, p = idx & 7;
    int s = p ^ (key & 7);
    stage16(kbase + (size_t)(key0 + key) * 512 + cd * 64 + s * 8,
            buf + (size_t)(wave * 128 + i * 64) * 8);
  }
}
// V chunk: 64 d (cv*64..) x 64 keys -> 8KB.
// granule idx: dl = idx>>3, p = idx&7, s = p^(dl&7)
__device__ __forceinline__ void issueV8(const bf16_t* vbase, int key0, int cv,
                                        bf16_t* buf, int wave, int lane) {
#pragma unroll
  for (int i = 0; i < 2; ++i) {
    int idx = wave * 128 + i * 64 + lane;
    int dl = idx >> 3, p = idx & 7;
    int s = p ^ (dl & 7);
    stage16(vbase + (size_t)(cv * 64 + dl) * 2048 + key0 + s * 8,
            buf + (size_t)(wave * 128 + i * 64) * 8);
  }
}

// ------------------------------- attention ----------------------------------
// 816 jobs: batch = blockIdx&7 (XCD pin), jj = blockIdx>>3 in 0..101 decodes
// (t desc from 31, n_t = ceil((t+1)/6) chunks). Block = 64 q-rows, 4 waves.
// Per kb: 16 phases of 8KB chunks (K0..K7, V0..V7). Tri-buffer (chunk -> %3);
// chunk j+1 issued at phase j start (buf last read at phase j-2: WAR-safe),
// waited at phase j+1 via vmcnt(2). LDS 33.8KB -> 4 blocks/CU by LDS.
__global__ __launch_bounds__(256, 2) void attn_kernel(
    const bf16_t* __restrict__ qg, const bf16_t* __restrict__ kg,
    const bf16_t* __restrict__ vTg, float* __restrict__ out,
    bf16_t* __restrict__ Opart, float* __restrict__ msum, float* __restrict__ lsum) {
  __shared__ __align__(16) bf16_t Pipe[3][4096];       // 24KB tri-buffer (8KB each)
  __shared__ __align__(16) bf16_t Plds[4][16 * XSTR];  // 9.2KB per-wave P

  int bid = blockIdx.x;
  int b = bid & 7, jj = bid >> 3;
  int t = 31, base = 0, n = 6;
  for (;;) {
    int nt_ = (t + 6) / 6;
    if (jj < base + nt_) { n = nt_; break; }
    base += nt_; --t;
  }
  int c = jj - base;
  int kbs = t + 1;
  int csz = (kbs + n - 1) / n;
  int kb_lo = c * csz;
  int kb_hi = min(kbs, kb_lo + csz);
  int q0 = t * 64;

  int tid = threadIdx.x;
  int wave = tid >> 6, lane = tid & 63, lhi = lane >> 4, llo = lane & 15;
  bf16_t* Pb = &Plds[wave][0];

  const bf16_t* kbase = kg + ((size_t)b << 11) * 512;
  const bf16_t* vbase = vTg + ((size_t)b << 9) * 2048;

  int bc = 0;  // compute buffer (= chunk index % 3)
  issueK8(kbase, kb_lo * 64, 0, &Pipe[0][0], wave, lane);

  // Q fragments (A-layout m=llo, k=lhi*8+j), rows q0+wave*16+llo, all 512 d
  const bf16_t* qrowp = qg + (size_t)((b << 11) + q0 + wave * 16 + llo) * 512;
  bf16x8 qf[16];
#pragma unroll
  for (int kk = 0; kk < 16; ++kk)
    qf[kk] = *(const bf16x8*)(qrowp + kk * 32 + lhi * 8);

  f32x4 Of[32];
#pragma unroll
  for (int i = 0; i < 32; ++i) Of[i] = (f32x4){0.f, 0.f, 0.f, 0.f};
  float m_i[4] = {-INFINITY, -INFINITY, -INFINITY, -INFINITY};
  float l_i[4] = {0.f, 0.f, 0.f, 0.f};

  for (int kb = kb_lo; kb < kb_hi; ++kb) {
    int key0 = kb * 64;
    bool more = (kb + 1 < kb_hi);
    f32x4 sf[4];
#pragma unroll
    for (int nt = 0; nt < 4; ++nt) sf[nt] = (f32x4){0.f, 0.f, 0.f, 0.f};

    // ---- QK: 8 phases of 64-d K chunks; issue chunk j+1 at phase j ----
#pragma unroll
    for (int cd = 0; cd < 8; ++cd) {
      int nb = (bc + 1 == 3) ? 0 : bc + 1;
      if (cd < 7) issueK8(kbase, key0, cd + 1, &Pipe[nb][0], wave, lane);
      else        issueV8(vbase, key0, 0, &Pipe[nb][0], wave, lane);
      PW_MORE;
      const bf16_t* bufc = &Pipe[bc][0];
#pragma unroll
      for (int kkl = 0; kkl < 2; ++kkl) {
#pragma unroll
        for (int nt = 0; nt < 4; ++nt) {
          bf16x8 kf = *(const bf16x8*)(bufc + (nt * 16 + llo) * 64 +
                                       (((kkl * 4 + lhi) ^ (llo & 7)) * 8));
          sf[nt] = MFMA16(qf[cd * 2 + kkl], kf, sf[nt]);
        }
      }
      bc = nb;
    }

    // ---- softmax (V0 DMA in flight underneath) ----
    if (kb == t) {  // diagonal block: causal mask
#pragma unroll
      for (int nt = 0; nt < 4; ++nt) {
        int kloc = nt * 16 + llo;
#pragma unroll
        for (int r = 0; r < 4; ++r)
          if (kloc > wave * 16 + lhi * 4 + r) sf[nt][r] = -INFINITY;
      }
    }
    float vm[4];
#pragma unroll
    for (int r = 0; r < 4; ++r) {
      vm[r] = fmaxf(fmaxf(sf[0][r], sf[1][r]), fmaxf(sf[2][r], sf[3][r]));
      vm[r] = fmaxf(vm[r], __shfl_xor(vm[r], 1, 64));
      vm[r] = fmaxf(vm[r], __shfl_xor(vm[r], 2, 64));
      vm[r] = fmaxf(vm[r], __shfl_xor(vm[r], 4, 64));
      vm[r] = fmaxf(vm[r], __shfl_xor(vm[r], 8, 64));
    }
    float alpha[4];
    int resc = 0;
#pragma unroll
    for (int r = 0; r < 4; ++r) {
      float mn = fmaxf(m_i[r], vm[r]);
      alpha[r] = __expf(m_i[r] - mn);
      m_i[r] = mn;
      resc |= (alpha[r] < 1.0f) ? 1 : 0;
    }
#pragma unroll
    for (int r = 0; r < 4; ++r) {
      float ps = 0.f;
#pragma unroll
      for (int nt = 0; nt < 4; ++nt) {
        float p2 = __expf(sf[nt][r] - m_i[r]);
        ps += p2;
        Pb[(lhi * 4 + r) * XSTR + nt * 16 + llo] = (bf16_t)p2;
      }
      l_i[r] = alpha[r] * l_i[r] + ps;
    }
    if (__any(resc)) {
#pragma unroll
      for (int i = 0; i < 32; ++i)
#pragma unroll
        for (int r = 0; r < 4; ++r) Of[i][r] *= alpha[r];
    }

    // ---- PV: 8 phases of 64-d V chunks; last phase issues next kb's K0 ----
#pragma unroll
    for (int cv = 0; cv < 8; ++cv) {
      int nb = (bc + 1 == 3) ? 0 : bc + 1;
      bool last = (cv == 7) && !more;
      if (cv < 7)      issueV8(vbase, key0, cv + 1, &Pipe[nb][0], wave, lane);
      else if (more)   issueK8(kbase, key0 + 64, 0, &Pipe[nb][0], wave, lane);
      if (last) PW_LAST else PW_MORE;
      const bf16_t* bufc = &Pipe[bc][0];
#pragma unroll
      for (int ks = 0; ks < 2; ++ks) {
        bf16x8 pa = *(const bf16x8*)(&Pb[llo * XSTR + ks * 32 + lhi * 8]);
#pragma unroll
        for (int ntl = 0; ntl < 4; ++ntl) {
          bf16x8 bv = *(const bf16x8*)(bufc + (ntl * 16 + llo) * 64 +
                                       (((ks * 4 + lhi) ^ (llo & 7)) * 8));
          Of[cv * 4 + ntl] = MFMA16(pa, bv, Of[cv * 4 + ntl]);
        }
      }
      bc = nb;
    }
  }  // kb loop

  // l reduction across the 16 col-lanes
#pragma unroll
  for (int r = 0; r < 4; ++r) {
    l_i[r] += __shfl_xor(l_i[r], 1, 64);
    l_i[r] += __shfl_xor(l_i[r], 2, 64);
    l_i[r] += __shfl_xor(l_i[r], 4, 64);
    l_i[r] += __shfl_xor(l_i[r], 8, 64);
  }

  // Of[i] holds d-col = i*16 + llo
  if (n == 1) {
    float linv[4];
#pragma unroll
    for (int r = 0; r < 4; ++r) linv[r] = 1.0f / l_i[r];
    float* ob = out + (size_t)((b << 11) + q0 + wave * 16) * 512;
#pragma unroll
    for (int i = 0; i < 32; ++i) {
      int dcol = i * 16 + llo;
#pragma unroll
      for (int r = 0; r < 4; ++r)
        __builtin_nontemporal_store(Of[i][r] * linv[r],
                                    &ob[(size_t)(lhi * 4 + r) * 512 + dcol]);
    }
  } else {
    bf16_t* op = Opart + (size_t)bid * (64 * 512) + (size_t)(wave * 16) * 512;
#pragma unroll
    for (int i = 0; i < 32; ++i) {
      int dcol = i * 16 + llo;
#pragma unroll
      for (int r = 0; r < 4; ++r)
        __builtin_nontemporal_store((bf16_t)Of[i][r],
                                    &op[(size_t)(lhi * 4 + r) * 512 + dcol]);
    }
    if (llo == 0) {
#pragma unroll
      for (int r = 0; r < 4; ++r) {
        msum[bid * 64 + wave * 16 + lhi * 4 + r] = m_i[r];
        lsum[bid * 64 + wave * 16 + lhi * 4 + r] = l_i[r];
      }
    }
  }
}

// ------------------------------- merge --------------------------------------
// Combine 2-6 partials for tiles 6..31 of each batch.
__global__ __launch_bounds__(256) void merge_kernel(const bf16_t* __restrict__ Opart,
                                                    const float* __restrict__ msum,
                                                    const float* __restrict__ lsum,
                                                    float* __restrict__ out) {
  int idx = blockIdx.x * 256 + threadIdx.x;  // 8*26*64*512 = 6,815,744
  int d = idx & 511;
  int rg = idx >> 9;          // 0..13311 = b(8) x t(26) x row(64)
  int b = rg / 1664;
  int rr = rg - b * 1664;
  int t = 6 + (rr >> 6), row = rr & 63;
  int base = 0;
  for (int s = 31; s > t; --s) base += (s + 6) / 6;
  int n = (t + 6) / 6;
  float M = -INFINITY;
  for (int c2 = 0; c2 < n; ++c2)
    M = fmaxf(M, msum[((base + c2) * 8 + b) * 64 + row]);
  float denom = 0.f, acc = 0.f;
  for (int c2 = 0; c2 < n; ++c2) {
    int j = (base + c2) * 8 + b;
    float a = __expf(msum[j * 64 + row] - M);
    denom += a * lsum[j * 64 + row];
    bf16_t ov = __builtin_nontemporal_load(&Opart[(size_t)j * (64 * 512) + row * 512 + d]);
    acc += a * (float)ov;
  }
  __builtin_nontemporal_store(acc / denom,
                              &out[(size_t)((b << 11) + (t << 6) + row) * 512 + d]);
}

// ------------------------------- launcher -----------------------------------
extern "C" void kernel_launch(void* const* d_in, const int* in_sizes, int n_in,
                              void* d_out, int out_size, void* d_ws, size_t ws_size,
                              hipStream_t stream) {
  (void)in_sizes; (void)n_in; (void)out_size; (void)ws_size;
  const float* x0 = (const float*)d_in[0];
  const float* x1 = (const float*)d_in[1];
  const float* x2 = (const float*)d_in[2];
  const float* Wq = (const float*)d_in[3];
  const float* bq = (const float*)d_in[4];
  const float* Wk = (const float*)d_in[5];
  const float* bk = (const float*)d_in[6];
  float* out = (float*)d_out;
  char* ws = (char*)d_ws;
  const size_t MB = 1ull << 20;
  bf16_t* Wtq = (bf16_t*)(ws + 0 * MB);             // 1 MB
  bf16_t* Wtk = (bf16_t*)(ws + 1 * MB);             // 1 MB
  bf16_t* qw  = (bf16_t*)(ws + 2 * MB);             // 16 MB
  bf16_t* kw  = (bf16_t*)(ws + 18 * MB);            // 16 MB
  bf16_t* vT  = (bf16_t*)(ws + 34 * MB);            // 16 MB
  float* msum = (float*)(ws + 50 * MB);             // 209 KB (816*64*4)
  float* lsum = (float*)(ws + 50 * MB + (512 << 10));
  bf16_t* Opart = (bf16_t*)(ws + 51 * MB);          // 53.5 MB (816*64*512*2)

  hipLaunchKernelGGL(wt_kernel, dim3(1024), dim3(256), 0, stream, Wq, Wk, Wtq, Wtk);
  hipLaunchKernelGGL(proj_kernel, dim3(1536), dim3(256), 0, stream,
                     x0, x1, x2, Wtq, Wtk, bq, bk, qw, kw, vT);
  hipLaunchKernelGGL(attn_kernel, dim3(816), dim3(256), 0, stream,
                     qw, kw, vT, out, Opart, msum, lsum);
  hipLaunchKernelGGL(merge_kernel, dim3(26624), dim3(256), 0, stream,
                     Opart, msum, lsum, out);
}